// Round 17
// baseline (77.015 us; speedup 1.0000x reference)
//
#include <hip/hip_runtime.h>
#include <hip/hip_bf16.h>

#define NB 8
#define NU 8192
#define GN0 64
#define GN1 64
#define NS 4096
#define NE 128
#define NH 8
#define CAP 20
#define NPTS (NB * NU)               // 65536
#define NCELL (NB * NS)              // 32768
#define OUT0 (NB * GN0 * GN1 * 2)    // 65536 f32 passthrough

// ---------------------------------------------------------------------------
// ws layout (bytes), total ~37.2 MB:
//   counts @ 0        (131072)   int32 per cell (zeroed by setup blocks)
//   lists  @ 131072   (1310720)  u16 point ids per cell
//   qf     @ 1441792  (2097152)  f32 [NS][128] q = latents @ Wq
//   fakeKV @ 3538944  (1024)     f32 fakeK[128], fakeV[128]
//   Wt     @ 3539968  (65536)    bf16 [256][128]: rows 0..127 Wv^T, 128..255 Wk^T
//   Wot    @ 3605504  (32768)    bf16 Wo^T [col][k]
//   Vb     @ 3638272  (16777216) bf16 V = Z @ Wv
//   Kb     @ 20415488 (16777216) bf16 K = Z @ Wk
//
// r15/r16 evidence: vgemm ~40us with ALL pipes idle (Mfma 3.6, VALU 12,
// HBM 18, Occ 23) -> the staging->LDS->block-barrier chain is the latency.
// r17 fix: LDS-FREE vgemm. Wave = 32 points x 64 ch; A-frags loaded directly
// from f32 z with MFMA per-lane addressing (per (st,ks): 16 rows x 128B =
// 16 full cache lines), cvt in-register; no barrier, waves fully independent.
// r13 lesson: don't starve VGPR. r14 lesson: loop-form attn gathers.
// ---------------------------------------------------------------------------

typedef __attribute__((ext_vector_type(8))) short short8v;
typedef __attribute__((ext_vector_type(4))) float float4v;

static __device__ inline unsigned pk2(float a, float b) {
  __hip_bfloat16 x = __float2bfloat16(a), y = __float2bfloat16(b);
  return ((unsigned)*(unsigned short*)&y << 16) | *(unsigned short*)&x;
}
static __device__ inline float bfs(short v) {
  unsigned u = (unsigned)(unsigned short)v << 16;
  return __builtin_bit_cast(float, u);
}

// block-range dispatch (129 blocks):
//   0..63   : out0 passthrough copy (float4) + counts zero (int4)
//   64      : fakeKV row
//   65..128 : Wv^T / Wk^T -> Wt, Wo^T -> Wot (bf16)
__global__ __launch_bounds__(256) void setup_kernel(
    const float* __restrict__ xc_on, const float* __restrict__ fake,
    const float* __restrict__ Wk, const float* __restrict__ Wv,
    const float* __restrict__ Wo,
    float* __restrict__ out, int* __restrict__ counts,
    float* __restrict__ fakeKV, __hip_bfloat16* __restrict__ Wt,
    __hip_bfloat16* __restrict__ Wot) {
  int t = threadIdx.x;
  int blk = blockIdx.x;
  if (blk < 64) {
    int idx = blk * 256 + t;             // 0..16383
    ((float4*)out)[idx] = ((const float4*)xc_on)[idx];
    if (idx < NCELL / 4) ((int4*)counts)[idx] = int4{0, 0, 0, 0};
    return;
  }
  if (blk == 64) {
    __shared__ float frow[NE];
    if (t < NE) frow[t] = fake[t];
    __syncthreads();
    int e = t & 127, half = t >> 7;
    const float* W = half ? Wv : Wk;
    float acc = 0.f;
    for (int j = 0; j < NE; ++j) acc += frow[j] * W[j * NE + e];
    fakeKV[half * NE + e] = acc;    // [0:128)=fakeK, [128:256)=fakeV
    return;
  }
  {
    int flat = (blk - 65) * 256 + t;     // 0..16383 ; j=row, e=col
    int j = flat >> 7, e = flat & 127;
    Wt[e * NE + j] = __float2bfloat16(Wv[flat]);            // Wv^T rows 0..127
    Wt[(128 + e) * NE + j] = __float2bfloat16(Wk[flat]);    // Wk^T rows 128..255
    Wot[e * NE + j] = __float2bfloat16(Wo[flat]);
  }
}

// blocks 0..511    : qf = latents @ Wq (f32, 8 rows/block)
// blocks 512..2559 : nearest + [V|K] = bf16(Z @ [Wv|Wk]) MFMA, LDS-free.
//   Logical blk covers 32 points; wave w covers output channels w*64..+63
//   (w<2 -> V, w>=2 -> K). A-frags loaded DIRECTLY from f32 z, cvt in-reg;
//   no staging, no barrier. Batch-pinned XCD swizzle (512%8==0 preserved).
__global__ __launch_bounds__(256) void vgemm_qf_kernel(
    const float* __restrict__ z, const float* __restrict__ xc_off,
    const float* __restrict__ xc_on, const __hip_bfloat16* __restrict__ Wt,
    const float* __restrict__ latents, const float* __restrict__ Wq,
    int* __restrict__ counts, unsigned short* __restrict__ lists,
    __hip_bfloat16* __restrict__ Vb, __hip_bfloat16* __restrict__ Kb,
    float* __restrict__ qf) {
  __shared__ float lrow[8 * NE];         // used by qf role only (4 KB)
  int tid = threadIdx.x;
  if ((int)blockIdx.x < 512) {
    // ---- qf role ----
    int s0 = (int)blockIdx.x * 8;
    for (int i = tid; i < 8 * NE; i += 256)
      lrow[i] = latents[(size_t)s0 * NE + i];
    __syncthreads();
    for (int i = tid; i < 8 * NE; i += 256) {
      int sl = i >> 7, e = i & 127;
      float acc = 0.f;
      for (int j = 0; j < NE; ++j) acc += lrow[sl * NE + j] * Wq[j * NE + e];
      qf[(size_t)(s0 + sl) * NE + e] = acc;
    }
    return;
  }
  // ---- vgemm role ----
  int hw = (int)blockIdx.x - 512;        // 0..2047
  int blk = (hw & 7) * 256 + (hw >> 3);  // batch = blk>>8 = hw&7 (XCD-pinned)
  size_t p0 = (size_t)blk * 32;
  if (tid < 32) {                        // nearest: one lane per point
    int p = (int)p0 + tid;
    int b = p >> 13;
    const float* g = xc_on + (size_t)b * (GN0 * GN1 * 2);
    float c00 = g[0], c01 = g[GN1 * 2], c10 = g[1], c11 = g[3];
    float x0 = xc_off[(size_t)p * 2 + 0];
    float x1 = xc_off[(size_t)p * 2 + 1];
    float f0 = rintf((x0 - c00) / (c01 - c00));   // np.round = RNE
    float f1 = rintf((x1 - c10) / (c11 - c10));
    int i0 = (int)fminf(fmaxf(f0, 0.f), 63.f);
    int i1 = (int)fminf(fmaxf(f1, 0.f), 63.f);
    int cell = b * NS + i0 * GN1 + i1;
    int pos = atomicAdd(&counts[cell], 1);
    if (pos < CAP) lists[cell * CAP + pos] = (unsigned short)p;
  }
  int w = tid >> 6, l = tid & 63;
  int lr = l & 15, lk = l >> 4;
  // A-fragments direct from global f32 z (per (st,ks): wave covers 16 rows
  // x 128 contiguous bytes = 16 fully-used cache lines)
  short8v afr[2][4];
#pragma unroll
  for (int st = 0; st < 2; ++st)
#pragma unroll
    for (int ks = 0; ks < 4; ++ks) {
      const float* src = &z[(p0 + st * 16 + lr) * NE + ks * 32 + lk * 8];
      float4 x = *(const float4*)src;
      float4 y = *(const float4*)(src + 4);
      uint4 u = {pk2(x.x, x.y), pk2(x.z, x.w), pk2(y.x, y.y), pk2(y.z, y.w)};
      afr[st][ks] = __builtin_bit_cast(short8v, u);
    }
  // B-fragments from L2-hot Wt; wave w owns channels w*64..+63 of [V|K]
  const short* Wg = (const short*)Wt;
  short8v bfrag[4][4];
#pragma unroll
  for (int ct = 0; ct < 4; ++ct) {
    int col = w * 64 + ct * 16 + lr;
#pragma unroll
    for (int ks = 0; ks < 4; ++ks)
      bfrag[ct][ks] = *(const short8v*)&Wg[col * NE + ks * 32 + lk * 8];
  }
  float4v acc[2][4] = {};
#pragma unroll
  for (int ks = 0; ks < 4; ++ks)
#pragma unroll
    for (int st = 0; st < 2; ++st)
#pragma unroll
      for (int ct = 0; ct < 4; ++ct)   // swapped operands: result is C^T
        acc[st][ct] = __builtin_amdgcn_mfma_f32_16x16x32_bf16(
            bfrag[ct][ks], afr[st][ks], acc[st][ct], 0, 0, 0);
  __hip_bfloat16* dst = (w < 2) ? Vb : Kb;
  int cb = (w & 1) * 64;                 // channel base within 128-wide output
#pragma unroll
  for (int st = 0; st < 2; ++st)
#pragma unroll
    for (int ct = 0; ct < 4; ++ct) {
      size_t point = p0 + st * 16 + lr;
      int ch = cb + ct * 16 + lk * 4;    // 4 consecutive channels
      uint2 u = {pk2(acc[st][ct][0], acc[st][ct][1]),
                 pk2(acc[st][ct][2], acc[st][ct][3])};
      *(uint2*)&dst[point * NE + ch] = u;   // 8B aligned
    }
}

// fused scores + softmax + PV + Wo: 16 cells/block, 4 waves, one cell per
// 16-lane group. Lane i owns dims 8i..8i+7 (16B K/V loads); score reduce is
// one shfl_xor. Batch-pinned XCD swizzle matches vgemm.
__global__ __launch_bounds__(256) void attn_wo_kernel(
    const __hip_bfloat16* __restrict__ Vb, const __hip_bfloat16* __restrict__ Kb,
    const float* __restrict__ qf, const float* __restrict__ fakeKV,
    const int* __restrict__ counts, const unsigned short* __restrict__ lists,
    const __hip_bfloat16* __restrict__ Wot, float* __restrict__ out) {
  __shared__ __hip_bfloat16 ob[16 * 136];   // O tile (bf16)
  __shared__ float sc[4][4][24][8];         // [wave][group][token][head]
  __shared__ unsigned short pl[4][4][24];
  int tid = threadIdx.x, w = tid >> 6, l = tid & 63;
  int g = l >> 4, i = l & 15;
  int blk = ((int)blockIdx.x & 7) * 256 + ((int)blockIdx.x >> 3);
  int row = w * 4 + g;
  int cell = blk * 16 + row;
  int s = cell & (NS - 1);
  int cnt = min(counts[cell], CAP);
  for (int t = i; t < cnt; t += 16)
    pl[w][g][t] = lists[cell * CAP + t];
  int d0 = i * 8;
  float4 qa = *(const float4*)&qf[(size_t)s * NE + d0];
  float4 qb = *(const float4*)&qf[(size_t)s * NE + d0 + 4];
  __builtin_amdgcn_wave_barrier();
  // scores: head h = i>>1 spans lanes {2h, 2h+1}
  for (int t = 0; t < cnt; ++t) {
    int pid = pl[w][g][t];
    short8v kv = *(const short8v*)(const short*)(Kb + (size_t)pid * NE + d0);
    float p = qa.x * bfs(kv[0]) + qa.y * bfs(kv[1]) + qa.z * bfs(kv[2]) + qa.w * bfs(kv[3])
            + qb.x * bfs(kv[4]) + qb.y * bfs(kv[5]) + qb.z * bfs(kv[6]) + qb.w * bfs(kv[7]);
    p += __shfl_xor(p, 1);
    if ((i & 1) == 0) sc[w][g][t][i >> 1] = p * 0.25f;
  }
  {
    float4 fa = *(const float4*)&fakeKV[d0];
    float4 fb = *(const float4*)&fakeKV[d0 + 4];
    float p = qa.x * fa.x + qa.y * fa.y + qa.z * fa.z + qa.w * fa.w
            + qb.x * fb.x + qb.y * fb.y + qb.z * fb.z + qb.w * fb.w;
    p += __shfl_xor(p, 1);
    if ((i & 1) == 0) sc[w][g][cnt][i >> 1] = p * 0.25f;
  }
  __builtin_amdgcn_wave_barrier();
  if (i < 8) {                        // lane i handles head i of its group
    int T = cnt + 1;
    float m = -1e30f;
    for (int t = 0; t < T; ++t) m = fmaxf(m, sc[w][g][t][i]);
    float sum = 0.f;
    for (int t = 0; t < T; ++t) {
      float e = __expf(sc[w][g][t][i] - m);
      sum += e;
      sc[w][g][t][i] = e;
    }
    float inv = 1.f / sum;
    for (int t = 0; t < T; ++t) sc[w][g][t][i] *= inv;
  }
  __builtin_amdgcn_wave_barrier();
  // PV: lane accumulates its 8 dims
  int h = i >> 1;
  float va[8] = {0.f, 0.f, 0.f, 0.f, 0.f, 0.f, 0.f, 0.f};
  for (int t = 0; t < cnt; ++t) {
    int pid = pl[w][g][t];
    short8v vv = *(const short8v*)(const short*)(Vb + (size_t)pid * NE + d0);
    float wt = sc[w][g][t][h];
#pragma unroll
    for (int j = 0; j < 8; ++j) va[j] += wt * bfs(vv[j]);
  }
  {
    float4 fa = *(const float4*)&fakeKV[NE + d0];
    float4 fb = *(const float4*)&fakeKV[NE + d0 + 4];
    float wt = sc[w][g][cnt][h];
    va[0] += wt * fa.x; va[1] += wt * fa.y; va[2] += wt * fa.z; va[3] += wt * fa.w;
    va[4] += wt * fb.x; va[5] += wt * fb.y; va[6] += wt * fb.z; va[7] += wt * fb.w;
  }
  {
    uint4 u = {pk2(va[0], va[1]), pk2(va[2], va[3]),
               pk2(va[4], va[5]), pk2(va[6], va[7])};
    *(uint4*)&ob[row * 136 + d0] = u;   // byte offset row*272 + i*16, 16B aligned
  }
  __syncthreads();
  // Wo MFMA epilogue: wave w covers col tiles {2w, 2w+1}, all 16 rows
  int lr = l & 15, lk = l >> 4;
  const short* ol = (const short*)ob;
  const short* Wg = (const short*)Wot;
  short8v afr[4];
#pragma unroll
  for (int ks = 0; ks < 4; ++ks)
    afr[ks] = *(const short8v*)&ol[lr * 136 + ks * 32 + lk * 8];
  float4v acc[2] = {};
#pragma unroll
  for (int ct = 0; ct < 2; ++ct) {
    int col = (w * 2 + ct) * 16 + lr;
#pragma unroll
    for (int ks = 0; ks < 4; ++ks) {
      short8v bfr = *(const short8v*)&Wg[col * NE + ks * 32 + lk * 8];
      acc[ct] = __builtin_amdgcn_mfma_f32_16x16x32_bf16(afr[ks], bfr, acc[ct], 0, 0, 0);
    }
  }
  float* base = out + (size_t)OUT0 + (size_t)blk * 16 * NE;
#pragma unroll
  for (int ct = 0; ct < 2; ++ct)
#pragma unroll
    for (int r = 0; r < 4; ++r) {
      int orow = lk * 4 + r;
      int col = (w * 2 + ct) * 16 + lr;
      base[(size_t)orow * NE + col] = acc[ct][r];
    }
}

extern "C" void kernel_launch(void* const* d_in, const int* in_sizes, int n_in,
                              void* d_out, int out_size, void* d_ws, size_t ws_size,
                              hipStream_t stream) {
  const float* xc_off  = (const float*)d_in[0];
  const float* xc_on   = (const float*)d_in[1];
  const float* zc_off  = (const float*)d_in[2];
  const float* latents = (const float*)d_in[4];
  const float* fake    = (const float*)d_in[5];
  const float* Wq      = (const float*)d_in[6];
  const float* Wk      = (const float*)d_in[7];
  const float* Wv      = (const float*)d_in[8];
  const float* Wo      = (const float*)d_in[9];
  float* out = (float*)d_out;

  char* ws = (char*)d_ws;
  int*            counts = (int*)(ws);
  unsigned short* lists  = (unsigned short*)(ws + 131072);
  float*          qf     = (float*)(ws + 1441792);
  float*          fakeKV = (float*)(ws + 3538944);
  __hip_bfloat16* Wt     = (__hip_bfloat16*)(ws + 3539968);
  __hip_bfloat16* Wot    = (__hip_bfloat16*)(ws + 3605504);
  __hip_bfloat16* Vb     = (__hip_bfloat16*)(ws + 3638272);
  __hip_bfloat16* Kb     = (__hip_bfloat16*)(ws + 20415488);

  hipLaunchKernelGGL(setup_kernel, dim3(129), dim3(256), 0, stream,
                     xc_on, fake, Wk, Wv, Wo, out, counts, fakeKV, Wt, Wot);
  hipLaunchKernelGGL(vgemm_qf_kernel, dim3(2560), dim3(256), 0, stream,
                     zc_off, xc_off, xc_on, Wt, latents, Wq,
                     counts, lists, Vb, Kb, qf);
  hipLaunchKernelGGL(attn_wo_kernel, dim3(NCELL / 16), dim3(256), 0, stream,
                     Vb, Kb, qf, fakeKV, counts, lists, Wot, out);
}

// Round 18
// 59.411 us; speedup vs baseline: 1.2963x; 1.2963x over previous
//
#include <hip/hip_runtime.h>
#include <hip/hip_bf16.h>

#define NB 8
#define NU 8192
#define GN0 64
#define GN1 64
#define NS 4096
#define NE 128
#define NH 8
#define CAP 20
#define NPTS (NB * NU)               // 65536
#define NCELL (NB * NS)              // 32768
#define OUT0 (NB * GN0 * GN1 * 2)    // 65536 f32 passthrough

// ---------------------------------------------------------------------------
// PROVEN-BEST configuration (r11/r15 = 59.50us). Reverted after r16 (C^T
// stores, neutral-negative) and r17 (LDS-free vgemm, -17us regression:
// 4x A-tile read amplification; the shared LDS z tile is load-bearing).
//
// ws layout (bytes), total ~37.2 MB:
//   counts @ 0        (131072)   int32 per cell (zeroed by setup blocks)
//   lists  @ 131072   (1310720)  u16 point ids per cell
//   qf     @ 1441792  (2097152)  f32 [NS][128] q = latents @ Wq
//   fakeKV @ 3538944  (1024)     f32 fakeK[128], fakeV[128]
//   Wt     @ 3539968  (65536)    bf16 [256][128]: rows 0..127 Wv^T, 128..255 Wk^T
//   Wot    @ 3605504  (32768)    bf16 Wo^T [col][k]
//   Vb     @ 3638272  (16777216) bf16 V = Z @ Wv
//   Kb     @ 20415488 (16777216) bf16 K = Z @ Wk
//
// Lessons encoded here: r13 (64-row tile; 32-row starves VGPR -> bfrag
// re-reads), r14 (loop-form attn gathers; compiler pipelines), r16 (normal
// operand order; C^T store shuffle not binding), r17 (keep LDS staging).
// XCD pinning: producer/consumer blocks of batch b share XCD b.
// ---------------------------------------------------------------------------

typedef __attribute__((ext_vector_type(8))) short short8v;
typedef __attribute__((ext_vector_type(4))) float float4v;

static __device__ inline unsigned pk2(float a, float b) {
  __hip_bfloat16 x = __float2bfloat16(a), y = __float2bfloat16(b);
  return ((unsigned)*(unsigned short*)&y << 16) | *(unsigned short*)&x;
}
static __device__ inline float bfs(short v) {
  unsigned u = (unsigned)(unsigned short)v << 16;
  return __builtin_bit_cast(float, u);
}

// block-range dispatch (129 blocks):
//   0..63   : out0 passthrough copy (float4) + counts zero (int4)
//   64      : fakeKV row
//   65..128 : Wv^T / Wk^T -> Wt, Wo^T -> Wot (bf16)
__global__ __launch_bounds__(256) void setup_kernel(
    const float* __restrict__ xc_on, const float* __restrict__ fake,
    const float* __restrict__ Wk, const float* __restrict__ Wv,
    const float* __restrict__ Wo,
    float* __restrict__ out, int* __restrict__ counts,
    float* __restrict__ fakeKV, __hip_bfloat16* __restrict__ Wt,
    __hip_bfloat16* __restrict__ Wot) {
  int t = threadIdx.x;
  int blk = blockIdx.x;
  if (blk < 64) {
    int idx = blk * 256 + t;             // 0..16383
    ((float4*)out)[idx] = ((const float4*)xc_on)[idx];
    if (idx < NCELL / 4) ((int4*)counts)[idx] = int4{0, 0, 0, 0};
    return;
  }
  if (blk == 64) {
    __shared__ float frow[NE];
    if (t < NE) frow[t] = fake[t];
    __syncthreads();
    int e = t & 127, half = t >> 7;
    const float* W = half ? Wv : Wk;
    float acc = 0.f;
    for (int j = 0; j < NE; ++j) acc += frow[j] * W[j * NE + e];
    fakeKV[half * NE + e] = acc;    // [0:128)=fakeK, [128:256)=fakeV
    return;
  }
  {
    int flat = (blk - 65) * 256 + t;     // 0..16383 ; j=row, e=col
    int j = flat >> 7, e = flat & 127;
    Wt[e * NE + j] = __float2bfloat16(Wv[flat]);            // Wv^T rows 0..127
    Wt[(128 + e) * NE + j] = __float2bfloat16(Wk[flat]);    // Wk^T rows 128..255
    Wot[e * NE + j] = __float2bfloat16(Wo[flat]);
  }
}

// blocks 0..1023 : nearest + [V|K] = bf16(Z @ [Wv|Wk]) MFMA, 64 rows/block
// blocks 1024..1535 : qf = latents @ Wq (f32, 8 rows/block) — overlapped.
__global__ __launch_bounds__(256) void vgemm_qf_kernel(
    const float* __restrict__ z, const float* __restrict__ xc_off,
    const float* __restrict__ xc_on, const __hip_bfloat16* __restrict__ Wt,
    const float* __restrict__ latents, const float* __restrict__ Wq,
    int* __restrict__ counts, unsigned short* __restrict__ lists,
    __hip_bfloat16* __restrict__ Vb, __hip_bfloat16* __restrict__ Kb,
    float* __restrict__ qf) {
  __shared__ __hip_bfloat16 zb[64 * 136];
  int tid = threadIdx.x;
  if ((int)blockIdx.x >= 1024) {
    // ---- qf role ----
    float* lrow = (float*)zb;            // alias LDS (4 KB of 17.4 KB)
    int s0 = ((int)blockIdx.x - 1024) * 8;
    for (int i = tid; i < 8 * NE; i += 256)
      lrow[i] = latents[(size_t)s0 * NE + i];
    __syncthreads();
    for (int i = tid; i < 8 * NE; i += 256) {
      int sl = i >> 7, e = i & 127;
      float acc = 0.f;
      for (int j = 0; j < NE; ++j) acc += lrow[sl * NE + j] * Wq[j * NE + e];
      qf[(size_t)(s0 + sl) * NE + e] = acc;
    }
    return;
  }
  // ---- vgemm role: 64-row tile, batch-pinned XCD swizzle ----
  int blk = ((int)blockIdx.x & 7) * 128 + ((int)blockIdx.x >> 3);
  size_t row0 = (size_t)blk * 64;
  for (int n = 0; n < 8; ++n) {
    int flat = n * 1024 + tid * 4;       // 0..8191 f32
    int r = flat >> 7, c = flat & 127;
    float4 v = *(const float4*)&z[(row0 + r) * NE + c];
    uint2 u = {pk2(v.x, v.y), pk2(v.z, v.w)};
    *(uint2*)&zb[r * 136 + c] = u;
  }
  if (tid < 64) {                        // nearest: one lane per point
    int p = (int)row0 + tid;
    int b = p >> 13;
    const float* g = xc_on + (size_t)b * (GN0 * GN1 * 2);
    float c00 = g[0], c01 = g[GN1 * 2], c10 = g[1], c11 = g[3];
    float x0 = xc_off[(size_t)p * 2 + 0];
    float x1 = xc_off[(size_t)p * 2 + 1];
    float f0 = rintf((x0 - c00) / (c01 - c00));   // np.round = RNE
    float f1 = rintf((x1 - c10) / (c11 - c10));
    int i0 = (int)fminf(fmaxf(f0, 0.f), 63.f);
    int i1 = (int)fminf(fmaxf(f1, 0.f), 63.f);
    int cell = b * NS + i0 * GN1 + i1;
    int pos = atomicAdd(&counts[cell], 1);
    if (pos < CAP) lists[cell * CAP + pos] = (unsigned short)p;
  }
  __syncthreads();
  int wid = tid >> 6, l = tid & 63;
  int lr = l & 15, lk = l >> 4;
  const short* zl = (const short*)zb;
  const short* Wg = (const short*)Wt;
  float4v acc[4][4] = {};
  short8v bfrag[4][4];
#pragma unroll
  for (int ct = 0; ct < 4; ++ct) {
    int col = wid * 64 + ct * 16 + lr;   // 0..255 across the 4 waves
#pragma unroll
    for (int ks = 0; ks < 4; ++ks)
      bfrag[ct][ks] = *(const short8v*)&Wg[col * NE + ks * 32 + lk * 8];
  }
#pragma unroll
  for (int ks = 0; ks < 4; ++ks)
#pragma unroll
    for (int st = 0; st < 4; ++st) {
      short8v a = *(const short8v*)&zl[(st * 16 + lr) * 136 + ks * 32 + lk * 8];
#pragma unroll
      for (int ct = 0; ct < 4; ++ct)
        acc[st][ct] = __builtin_amdgcn_mfma_f32_16x16x32_bf16(a, bfrag[ct][ks], acc[st][ct], 0, 0, 0);
    }
  __hip_bfloat16* dst = (wid < 2) ? Vb : Kb;
  int cb = (wid & 1) * 64;               // col base within the 128-wide output
#pragma unroll
  for (int st = 0; st < 4; ++st)
#pragma unroll
    for (int ct = 0; ct < 4; ++ct)
#pragma unroll
      for (int r = 0; r < 4; ++r) {
        size_t row = row0 + st * 16 + lk * 4 + r;
        int col = cb + ct * 16 + lr;
        dst[row * NE + col] = __float2bfloat16(acc[st][ct][r]);
      }
}

// fused scores + softmax + PV + Wo: 16 cells/block, 4 waves, one cell per
// 16-lane group. Lane i owns dims 8i..8i+7 (16B K/V loads); score reduce is
// one shfl_xor. Batch-pinned XCD swizzle matches vgemm.
__global__ __launch_bounds__(256) void attn_wo_kernel(
    const __hip_bfloat16* __restrict__ Vb, const __hip_bfloat16* __restrict__ Kb,
    const float* __restrict__ qf, const float* __restrict__ fakeKV,
    const int* __restrict__ counts, const unsigned short* __restrict__ lists,
    const __hip_bfloat16* __restrict__ Wot, float* __restrict__ out) {
  __shared__ __hip_bfloat16 ob[16 * 136];   // O tile (bf16)
  __shared__ float sc[4][4][24][8];         // [wave][group][token][head]
  __shared__ unsigned short pl[4][4][24];
  int tid = threadIdx.x, w = tid >> 6, l = tid & 63;
  int g = l >> 4, i = l & 15;
  int blk = ((int)blockIdx.x & 7) * 256 + ((int)blockIdx.x >> 3);
  int row = w * 4 + g;
  int cell = blk * 16 + row;
  int s = cell & (NS - 1);
  int cnt = min(counts[cell], CAP);
  for (int t = i; t < cnt; t += 16)
    pl[w][g][t] = lists[cell * CAP + t];
  int d0 = i * 8;
  float4 qa = *(const float4*)&qf[(size_t)s * NE + d0];
  float4 qb = *(const float4*)&qf[(size_t)s * NE + d0 + 4];
  __builtin_amdgcn_wave_barrier();
  // scores: head h = i>>1 spans lanes {2h, 2h+1}
  for (int t = 0; t < cnt; ++t) {
    int pid = pl[w][g][t];
    short8v kv = *(const short8v*)(const short*)(Kb + (size_t)pid * NE + d0);
    float p = qa.x * bfs(kv[0]) + qa.y * bfs(kv[1]) + qa.z * bfs(kv[2]) + qa.w * bfs(kv[3])
            + qb.x * bfs(kv[4]) + qb.y * bfs(kv[5]) + qb.z * bfs(kv[6]) + qb.w * bfs(kv[7]);
    p += __shfl_xor(p, 1);
    if ((i & 1) == 0) sc[w][g][t][i >> 1] = p * 0.25f;
  }
  {
    float4 fa = *(const float4*)&fakeKV[d0];
    float4 fb = *(const float4*)&fakeKV[d0 + 4];
    float p = qa.x * fa.x + qa.y * fa.y + qa.z * fa.z + qa.w * fa.w
            + qb.x * fb.x + qb.y * fb.y + qb.z * fb.z + qb.w * fb.w;
    p += __shfl_xor(p, 1);
    if ((i & 1) == 0) sc[w][g][cnt][i >> 1] = p * 0.25f;
  }
  __builtin_amdgcn_wave_barrier();
  if (i < 8) {                        // lane i handles head i of its group
    int T = cnt + 1;
    float m = -1e30f;
    for (int t = 0; t < T; ++t) m = fmaxf(m, sc[w][g][t][i]);
    float sum = 0.f;
    for (int t = 0; t < T; ++t) {
      float e = __expf(sc[w][g][t][i] - m);
      sum += e;
      sc[w][g][t][i] = e;
    }
    float inv = 1.f / sum;
    for (int t = 0; t < T; ++t) sc[w][g][t][i] *= inv;
  }
  __builtin_amdgcn_wave_barrier();
  // PV: lane accumulates its 8 dims
  int h = i >> 1;
  float va[8] = {0.f, 0.f, 0.f, 0.f, 0.f, 0.f, 0.f, 0.f};
  for (int t = 0; t < cnt; ++t) {
    int pid = pl[w][g][t];
    short8v vv = *(const short8v*)(const short*)(Vb + (size_t)pid * NE + d0);
    float wt = sc[w][g][t][h];
#pragma unroll
    for (int j = 0; j < 8; ++j) va[j] += wt * bfs(vv[j]);
  }
  {
    float4 fa = *(const float4*)&fakeKV[NE + d0];
    float4 fb = *(const float4*)&fakeKV[NE + d0 + 4];
    float wt = sc[w][g][cnt][h];
    va[0] += wt * fa.x; va[1] += wt * fa.y; va[2] += wt * fa.z; va[3] += wt * fa.w;
    va[4] += wt * fb.x; va[5] += wt * fb.y; va[6] += wt * fb.z; va[7] += wt * fb.w;
  }
  {
    uint4 u = {pk2(va[0], va[1]), pk2(va[2], va[3]),
               pk2(va[4], va[5]), pk2(va[6], va[7])};
    *(uint4*)&ob[row * 136 + d0] = u;   // byte offset row*272 + i*16, 16B aligned
  }
  __syncthreads();
  // Wo MFMA epilogue: wave w covers col tiles {2w, 2w+1}, all 16 rows
  int lr = l & 15, lk = l >> 4;
  const short* ol = (const short*)ob;
  const short* Wg = (const short*)Wot;
  short8v afr[4];
#pragma unroll
  for (int ks = 0; ks < 4; ++ks)
    afr[ks] = *(const short8v*)&ol[lr * 136 + ks * 32 + lk * 8];
  float4v acc[2] = {};
#pragma unroll
  for (int ct = 0; ct < 2; ++ct) {
    int col = (w * 2 + ct) * 16 + lr;
#pragma unroll
    for (int ks = 0; ks < 4; ++ks) {
      short8v bfr = *(const short8v*)&Wg[col * NE + ks * 32 + lk * 8];
      acc[ct] = __builtin_amdgcn_mfma_f32_16x16x32_bf16(afr[ks], bfr, acc[ct], 0, 0, 0);
    }
  }
  float* base = out + (size_t)OUT0 + (size_t)blk * 16 * NE;
#pragma unroll
  for (int ct = 0; ct < 2; ++ct)
#pragma unroll
    for (int r = 0; r < 4; ++r) {
      int orow = lk * 4 + r;
      int col = (w * 2 + ct) * 16 + lr;
      base[(size_t)orow * NE + col] = acc[ct][r];
    }
}

extern "C" void kernel_launch(void* const* d_in, const int* in_sizes, int n_in,
                              void* d_out, int out_size, void* d_ws, size_t ws_size,
                              hipStream_t stream) {
  const float* xc_off  = (const float*)d_in[0];
  const float* xc_on   = (const float*)d_in[1];
  const float* zc_off  = (const float*)d_in[2];
  const float* latents = (const float*)d_in[4];
  const float* fake    = (const float*)d_in[5];
  const float* Wq      = (const float*)d_in[6];
  const float* Wk      = (const float*)d_in[7];
  const float* Wv      = (const float*)d_in[8];
  const float* Wo      = (const float*)d_in[9];
  float* out = (float*)d_out;

  char* ws = (char*)d_ws;
  int*            counts = (int*)(ws);
  unsigned short* lists  = (unsigned short*)(ws + 131072);
  float*          qf     = (float*)(ws + 1441792);
  float*          fakeKV = (float*)(ws + 3538944);
  __hip_bfloat16* Wt     = (__hip_bfloat16*)(ws + 3539968);
  __hip_bfloat16* Wot    = (__hip_bfloat16*)(ws + 3605504);
  __hip_bfloat16* Vb     = (__hip_bfloat16*)(ws + 3638272);
  __hip_bfloat16* Kb     = (__hip_bfloat16*)(ws + 20415488);

  hipLaunchKernelGGL(setup_kernel, dim3(129), dim3(256), 0, stream,
                     xc_on, fake, Wk, Wv, Wo, out, counts, fakeKV, Wt, Wot);
  hipLaunchKernelGGL(vgemm_qf_kernel, dim3(1536), dim3(256), 0, stream,
                     zc_off, xc_off, xc_on, Wt, latents, Wq,
                     counts, lists, Vb, Kb, qf);
  hipLaunchKernelGGL(attn_wo_kernel, dim3(NCELL / 16), dim3(256), 0, stream,
                     Vb, Kb, qf, fakeKV, counts, lists, Wot, out);
}